// Round 1
// baseline (16111.270 us; speedup 1.0000x reference)
//
#include <hip/hip_runtime.h>
#include <hip/hip_cooperative_groups.h>

namespace cg = cooperative_groups;

#define NYg 256
#define NXg 256
#define NTg 256
#define NBg 2
#define NSRCg 2
#define NRECg 64
#define NYX (NYg*NXg)
#define NCELLS (NBg*NYX)

__global__ __launch_bounds__(256) void setup_kernel(
    const float* __restrict__ lamb, const float* __restrict__ mu,
    const float* __restrict__ buoy, float* __restrict__ coef)
{
  __shared__ float red[256];
  const int tid = threadIdx.x;
  float m = 0.0f;
  for (int i = tid; i < NYX; i += 256)
    m = fmaxf(m, sqrtf((lamb[i] + 2.0f*mu[i]) * buoy[i]));
  red[tid] = m;
  __syncthreads();
  for (int s = 128; s > 0; s >>= 1) {
    if (tid < s) red[tid] = fmaxf(red[tid], red[tid+s]);
    __syncthreads();
  }
  const float maxv = red[0];

  // PML coefficient tables (ny == nx == 256, DY == DX == 5 -> same tables)
  const float i_f = (float)tid;
  const float w = 20.0f;
  float f1 = fminf(fmaxf((w - i_f) * (1.0f/w), 0.0f), 1.0f);
  float f2 = fminf(fmaxf((i_f - (256.0f - 1.0f - w)) * (1.0f/w), 0.0f), 1.0f);
  float frac = fmaxf(f1, f2);
  float sigma_max = 3.0f * maxv * 6.907755278982137f / (2.0f * w * 5.0f);
  float sigma = sigma_max * frac * frac;
  float alpha = 3.14159265358979323f * 25.0f * (1.0f - frac);
  float bc = expf(-(sigma + alpha) * 0.0005f);
  float ac = sigma / (sigma + alpha + 1e-9f) * (bc - 1.0f);
  coef[tid]       = ac;  // ay
  coef[256 + tid] = bc;  // by
  coef[512 + tid] = ac;  // ax
  coef[768 + tid] = bc;  // bx
}

__global__ __launch_bounds__(512) void elastic_kernel(
    const float* __restrict__ lamb_g, const float* __restrict__ mu_g,
    const float* __restrict__ buoy_g, const float* __restrict__ amps,
    const int* __restrict__ src_loc, const int* __restrict__ rec_loc,
    float* __restrict__ fields, const float* __restrict__ coef,
    float* __restrict__ out)
{
  cg::grid_group grid = cg::this_grid();
  const int gid = blockIdx.x * 512 + threadIdx.x;   // 0..131071
  const int b   = gid >> 16;
  const int rem = gid & 0xFFFF;
  const int y   = rem >> 8;
  const int x   = rem & 0xFF;
  const int idx = gid;                              // b*NYX + y*NX + x

  float* __restrict__ vy_g  = fields;
  float* __restrict__ vx_g  = fields + NCELLS;
  float* __restrict__ syy_g = fields + 2*NCELLS;
  float* __restrict__ sxy_g = fields + 3*NCELLS;
  float* __restrict__ sxx_g = fields + 4*NCELLS;

  const int cell2  = y*NXg + x;
  const float buoyv = buoy_g[cell2];
  const float lambv = lamb_g[cell2];
  const float muv   = mu_g[cell2];
  const float l2mv  = lambv + 2.0f*muv;
  const float ayv = coef[y],       byv = coef[256 + y];
  const float axv = coef[512 + x], bxv = coef[768 + x];
  const float DT = 0.0005f;
  const float dtb = DT * buoyv;
  const float inv_dy = 1.0f/5.0f, inv_dx = 1.0f/5.0f;

  // --- source role: does this thread own a source cell? (<= NSRC matches) ---
  int scnt = 0; int sbase0 = 0, sbase1 = 0;
  for (int bs = 0; bs < NBg*NSRCg; ++bs) {
    int sb = bs >> 1;                       // NSRC == 2
    int sy = src_loc[2*bs], sx = src_loc[2*bs+1];
    if (sb == b && sy == y && sx == x) {
      if (scnt == 0) sbase0 = bs*NTg; else sbase1 = bs*NTg;
      ++scnt;
    }
  }

  // --- receiver role: first 128 threads each own one (b, rec) pair ---
  int rcell = -1; int rout = 0;
  if (gid < NBg*NRECg) {
    int rb = gid >> 6;                      // NREC == 64
    int ry = rec_loc[2*gid], rx = rec_loc[2*gid+1];
    rcell = rb*NYX + ry*NXg + rx;
    rout  = gid * NTg;                      // out[(rb*NREC + r)*NT + t]
  }

  // --- state: 5 coupled fields (regs + global), 8 CPML memories (regs only) ---
  float vyv = 0.0f, vxv = 0.0f, syyv = 0.0f, sxyv = 0.0f, sxxv = 0.0f;
  float m_syyy = 0.0f, m_sxyx = 0.0f, m_sxyy = 0.0f, m_sxxx = 0.0f;
  float m_vyy = 0.0f, m_vxx = 0.0f, m_vyx = 0.0f, m_vxy = 0.0f;

  vy_g[idx] = 0.0f; vx_g[idx] = 0.0f;
  syy_g[idx] = 0.0f; sxy_g[idx] = 0.0f; sxx_g[idx] = 0.0f;
  grid.sync();

  for (int t = 0; t < NTg; ++t) {
    // ---------------- phase A: velocity update ----------------
    float d = (y > 0) ? (syyv - syy_g[idx - NXg]) * inv_dy : 0.0f;   // dby(syy)
    m_syyy = byv*m_syyy + ayv*d;
    float accy = d + m_syyy;
    d = (x > 0) ? (sxyv - sxy_g[idx - 1]) * inv_dx : 0.0f;           // dbx(sxy)
    m_sxyx = bxv*m_sxyx + axv*d;
    accy += d + m_sxyx;
    vyv += dtb * accy;

    d = (y < NYg-1) ? (sxy_g[idx + NXg] - sxyv) * inv_dy : 0.0f;     // dfy(sxy)
    m_sxyy = byv*m_sxyy + ayv*d;
    float accx = d + m_sxyy;
    d = (x < NXg-1) ? (sxx_g[idx + 1] - sxxv) * inv_dx : 0.0f;       // dfx(sxx)
    m_sxxx = bxv*m_sxxx + axv*d;
    accx += d + m_sxxx;
    vxv += dtb * accx;

    if (scnt) {                                                      // source inject
      float a0 = amps[sbase0 + t];
      if (scnt > 1) a0 += amps[sbase1 + t];
      vyv += a0 * dtb;
    }
    vy_g[idx] = vyv;
    vx_g[idx] = vxv;
    grid.sync();

    // ---------------- recording (reads post-injection vy) ----------------
    if (rcell >= 0) out[rout + t] = vy_g[rcell];

    // ---------------- phase B: stress update ----------------
    d = (y < NYg-1) ? (vy_g[idx + NXg] - vyv) * inv_dy : 0.0f;       // dfy(vy)
    m_vyy = byv*m_vyy + ayv*d;
    float dyy = d + m_vyy;
    d = (x > 0) ? (vxv - vx_g[idx - 1]) * inv_dx : 0.0f;             // dbx(vx)
    m_vxx = bxv*m_vxx + axv*d;
    float dxx = d + m_vxx;
    syyv += DT * (l2mv*dyy + lambv*dxx);
    sxxv += DT * (lambv*dyy + l2mv*dxx);

    d = (x > 0) ? (vyv - vy_g[idx - 1]) * inv_dx : 0.0f;             // dbx(vy)
    m_vyx = bxv*m_vyx + axv*d;
    float dyx = d + m_vyx;
    d = (y > 0) ? (vxv - vx_g[idx - NXg]) * inv_dy : 0.0f;           // dby(vx)
    m_vxy = byv*m_vxy + ayv*d;
    float dxy = d + m_vxy;
    sxyv += DT * muv * (dyx + dxy);

    syy_g[idx] = syyv;
    sxy_g[idx] = sxyv;
    sxx_g[idx] = sxxv;
    grid.sync();
  }
}

extern "C" void kernel_launch(void* const* d_in, const int* in_sizes, int n_in,
                              void* d_out, int out_size, void* d_ws, size_t ws_size,
                              hipStream_t stream) {
  const float* lamb    = (const float*)d_in[0];
  const float* mu      = (const float*)d_in[1];
  const float* buoy    = (const float*)d_in[2];
  const float* amps    = (const float*)d_in[3];
  const int*   src_loc = (const int*)d_in[4];
  const int*   rec_loc = (const int*)d_in[5];
  float* out = (float*)d_out;
  float* ws  = (float*)d_ws;

  float* fields = ws;                 // 5 * NCELLS floats
  float* coef   = ws + 5*NCELLS;      // 1024 floats

  hipLaunchKernelGGL(setup_kernel, dim3(1), dim3(256), 0, stream,
                     lamb, mu, buoy, coef);

  void* args[] = { (void*)&lamb, (void*)&mu, (void*)&buoy, (void*)&amps,
                   (void*)&src_loc, (void*)&rec_loc, (void*)&fields,
                   (void*)&coef, (void*)&out };
  hipLaunchCooperativeKernel((void*)elastic_kernel, dim3(256), dim3(512),
                             args, 0, stream);
}

// Round 2
// 3203.563 us; speedup vs baseline: 5.0292x; 5.0292x over previous
//
#include <hip/hip_runtime.h>

#define NYg 256
#define NXg 256
#define NTg 256
#define NBg 2
#define NSRCg 2
#define NRECg 64
#define NYX (NYg*NXg)
#define NCELLS (NBg*NYX)
#define NBLOCKS 256           // 128 per batch, 2 rows each
#define FLAG_STRIDE 16        // uints (64B) between flags

__global__ __launch_bounds__(256) void setup_kernel(
    const float* __restrict__ lamb, const float* __restrict__ mu,
    const float* __restrict__ buoy, float* __restrict__ coef)
{
  __shared__ float red[256];
  const int tid = threadIdx.x;
  float m = 0.0f;
  for (int i = tid; i < NYX; i += 256)
    m = fmaxf(m, sqrtf((lamb[i] + 2.0f*mu[i]) * buoy[i]));
  red[tid] = m;
  __syncthreads();
  for (int s = 128; s > 0; s >>= 1) {
    if (tid < s) red[tid] = fmaxf(red[tid], red[tid+s]);
    __syncthreads();
  }
  const float maxv = red[0];

  const float i_f = (float)tid;
  const float w = 20.0f;
  float f1 = fminf(fmaxf((w - i_f) * (1.0f/w), 0.0f), 1.0f);
  float f2 = fminf(fmaxf((i_f - (256.0f - 1.0f - w)) * (1.0f/w), 0.0f), 1.0f);
  float frac = fmaxf(f1, f2);
  float sigma_max = 3.0f * maxv * 6.907755278982137f / (2.0f * w * 5.0f);
  float sigma = sigma_max * frac * frac;
  float alpha = 3.14159265358979323f * 25.0f * (1.0f - frac);
  float bc = expf(-(sigma + alpha) * 0.0005f);
  float ac = sigma / (sigma + alpha + 1e-9f) * (bc - 1.0f);
  coef[tid]       = ac;  // ay
  coef[256 + tid] = bc;  // by
  coef[512 + tid] = ac;  // ax
  coef[768 + tid] = bc;  // bx
}

__device__ __forceinline__ float ald(const float* p) {
  return __hip_atomic_load(p, __ATOMIC_RELAXED, __HIP_MEMORY_SCOPE_AGENT);
}
__device__ __forceinline__ void ast(float* p, float v) {
  __hip_atomic_store(p, v, __ATOMIC_RELAXED, __HIP_MEMORY_SCOPE_AGENT);
}

__global__ __launch_bounds__(512) void elastic_p2p(
    const float* __restrict__ lamb_g, const float* __restrict__ mu_g,
    const float* __restrict__ buoy_g, const float* __restrict__ amps,
    const int* __restrict__ src_loc, const int* __restrict__ rec_loc,
    float* __restrict__ fields, const float* __restrict__ coef,
    unsigned int* __restrict__ flags, float* __restrict__ out)
{
  const int bid = blockIdx.x;            // 0..255
  const int b   = bid >> 7;              // batch
  const int bi  = bid & 127;             // block-in-batch (2 rows each)
  const int tid = threadIdx.x;
  const int yl  = tid >> 8;              // 0/1
  const int x   = tid & 255;
  const int y   = (bi << 1) | yl;        // within-batch row
  const int idx = (b << 16) | (y << 8) | x;

  float* __restrict__ vy_g  = fields;
  float* __restrict__ vx_g  = fields + NCELLS;
  float* __restrict__ syy_g = fields + 2*NCELLS;
  float* __restrict__ sxy_g = fields + 3*NCELLS;
  float* __restrict__ sxx_g = fields + 4*NCELLS;

  const bool hasUp = bi > 0;
  const bool hasDn = bi < 127;
  unsigned int* fMe = flags + bid*FLAG_STRIDE;
  unsigned int* fUp = flags + (bid-1)*FLAG_STRIDE;
  unsigned int* fDn = flags + (bid+1)*FLAG_STRIDE;

  const int cell2  = y*NXg + x;
  const float buoyv = buoy_g[cell2];
  const float lambv = lamb_g[cell2];
  const float muv   = mu_g[cell2];
  const float l2mv  = lambv + 2.0f*muv;
  const float ayv = coef[y],       byv = coef[256 + y];
  const float axv = coef[512 + x], bxv = coef[768 + x];
  const float DT = 0.0005f;
  const float dtb = DT * buoyv;
  const float inv_d = 0.2f;   // 1/5.0

  // --- source ownership (up to 2 sources can share a cell) ---
  int scnt = 0; int sbase0 = 0, sbase1 = 0;
  for (int bs = 0; bs < NBg*NSRCg; ++bs) {
    int sb = bs >> 1;
    int sy = src_loc[2*bs], sx = src_loc[2*bs+1];
    if (sb == b && sy == y && sx == x) {
      if (scnt == 0) sbase0 = bs*NTg; else sbase1 = bs*NTg;
      ++scnt;
    }
  }

  // --- receiver ownership: 128-bit mask over (b,rec) pairs ---
  unsigned long long rm0 = 0ull, rm1 = 0ull;
  for (int k = 0; k < NBg*NRECg; ++k) {
    int rb = k >> 6;
    int ry = rec_loc[2*k], rx = rec_loc[2*k+1];
    if (rb == b && ry == y && rx == x) {
      if (k < 64) rm0 |= 1ull << k; else rm1 |= 1ull << (k-64);
    }
  }
  const bool isrec = (rm0 | rm1) != 0ull;

  // --- state in registers ---
  float vyv = 0.0f, vxv = 0.0f, syyv = 0.0f, sxyv = 0.0f, sxxv = 0.0f;
  float m_syyy = 0.0f, m_sxyx = 0.0f, m_sxyy = 0.0f, m_sxxx = 0.0f;
  float m_vyy = 0.0f, m_vxx = 0.0f, m_vyx = 0.0f, m_vxy = 0.0f;

  // zero the coupled fields (agent-scope so neighbors see them via L3)
  ast(&vy_g[idx], 0.0f);  ast(&vx_g[idx], 0.0f);
  ast(&syy_g[idx], 0.0f); ast(&sxy_g[idx], 0.0f); ast(&sxx_g[idx], 0.0f);
  __syncthreads();   // all stores complete (vmcnt drain)
  if (tid == 0)
    __hip_atomic_store(fMe, 1u, __ATOMIC_RELEASE, __HIP_MEMORY_SCOPE_AGENT);

  for (int t = 0; t < NTg; ++t) {
    const unsigned int tgtA = 2*t + 1;
    // ---- wait for neighbors' phase B of step t-1 (or init) ----
    if (tid < 2) {
      const bool has = (tid == 0) ? hasUp : hasDn;
      unsigned int* f = (tid == 0) ? fUp : fDn;
      if (has)
        while (__hip_atomic_load(f, __ATOMIC_RELAXED, __HIP_MEMORY_SCOPE_AGENT) < tgtA) {}
    }
    __syncthreads();

    // ---------------- phase A: velocity update ----------------
    float d = (y > 0) ? (syyv - ald(&syy_g[idx - NXg])) * inv_d : 0.0f;
    m_syyy = byv*m_syyy + ayv*d;
    float accy = d + m_syyy;
    d = (x > 0) ? (sxyv - ald(&sxy_g[idx - 1])) * inv_d : 0.0f;
    m_sxyx = bxv*m_sxyx + axv*d;
    accy += d + m_sxyx;
    vyv += dtb * accy;

    d = (y < NYg-1) ? (ald(&sxy_g[idx + NXg]) - sxyv) * inv_d : 0.0f;
    m_sxyy = byv*m_sxyy + ayv*d;
    float accx = d + m_sxyy;
    d = (x < NXg-1) ? (ald(&sxx_g[idx + 1]) - sxxv) * inv_d : 0.0f;
    m_sxxx = bxv*m_sxxx + axv*d;
    accx += d + m_sxxx;
    vxv += dtb * accx;

    if (scnt) {
      float a0 = amps[sbase0 + t];
      if (scnt > 1) a0 += amps[sbase1 + t];
      vyv += a0 * dtb;
    }
    ast(&vy_g[idx], vyv);
    ast(&vx_g[idx], vxv);

    // recording from the owning thread's register (post-injection)
    if (isrec) {
      unsigned long long m0 = rm0;
      while (m0) { int k = __ffsll((long long)m0) - 1; m0 &= m0 - 1; out[k*NTg + t] = vyv; }
      unsigned long long m1 = rm1;
      while (m1) { int k = __ffsll((long long)m1) - 1; m1 &= m1 - 1; out[(k+64)*NTg + t] = vyv; }
    }
    __syncthreads();   // all vy/vx stores complete
    if (tid == 0)
      __hip_atomic_store(fMe, 2*t + 2, __ATOMIC_RELEASE, __HIP_MEMORY_SCOPE_AGENT);

    // ---- wait for neighbors' phase A of step t ----
    const unsigned int tgtB = 2*t + 2;
    if (tid < 2) {
      const bool has = (tid == 0) ? hasUp : hasDn;
      unsigned int* f = (tid == 0) ? fUp : fDn;
      if (has)
        while (__hip_atomic_load(f, __ATOMIC_RELAXED, __HIP_MEMORY_SCOPE_AGENT) < tgtB) {}
    }
    __syncthreads();

    // ---------------- phase B: stress update ----------------
    d = (y < NYg-1) ? (ald(&vy_g[idx + NXg]) - vyv) * inv_d : 0.0f;
    m_vyy = byv*m_vyy + ayv*d;
    float dyy = d + m_vyy;
    d = (x > 0) ? (vxv - ald(&vx_g[idx - 1])) * inv_d : 0.0f;
    m_vxx = bxv*m_vxx + axv*d;
    float dxx = d + m_vxx;
    syyv += DT * (l2mv*dyy + lambv*dxx);
    sxxv += DT * (lambv*dyy + l2mv*dxx);

    d = (x > 0) ? (vyv - ald(&vy_g[idx - 1])) * inv_d : 0.0f;
    m_vyx = bxv*m_vyx + axv*d;
    float dyx = d + m_vyx;
    d = (y > 0) ? (vxv - ald(&vx_g[idx - NXg])) * inv_d : 0.0f;
    m_vxy = byv*m_vxy + ayv*d;
    float dxy = d + m_vxy;
    sxyv += DT * muv * (dyx + dxy);

    ast(&syy_g[idx], syyv);
    ast(&sxy_g[idx], sxyv);
    ast(&sxx_g[idx], sxxv);
    __syncthreads();   // all stress stores complete
    if (tid == 0)
      __hip_atomic_store(fMe, 2*t + 3, __ATOMIC_RELEASE, __HIP_MEMORY_SCOPE_AGENT);
  }
}

extern "C" void kernel_launch(void* const* d_in, const int* in_sizes, int n_in,
                              void* d_out, int out_size, void* d_ws, size_t ws_size,
                              hipStream_t stream) {
  const float* lamb    = (const float*)d_in[0];
  const float* mu      = (const float*)d_in[1];
  const float* buoy    = (const float*)d_in[2];
  const float* amps    = (const float*)d_in[3];
  const int*   src_loc = (const int*)d_in[4];
  const int*   rec_loc = (const int*)d_in[5];
  float* out = (float*)d_out;
  float* ws  = (float*)d_ws;

  float* fields = ws;                         // 5 * NCELLS floats
  float* coef   = ws + 5*NCELLS;              // 1024 floats
  unsigned int* flags = (unsigned int*)(ws + 5*NCELLS + 1024);  // 256*16 uints

  // flags must start at 0 every launch (monotonic counters within one launch)
  hipMemsetAsync(flags, 0, NBLOCKS*FLAG_STRIDE*sizeof(unsigned int), stream);

  hipLaunchKernelGGL(setup_kernel, dim3(1), dim3(256), 0, stream,
                     lamb, mu, buoy, coef);

  // cooperative launch only for the co-residency guarantee (no grid.sync used)
  void* args[] = { (void*)&lamb, (void*)&mu, (void*)&buoy, (void*)&amps,
                   (void*)&src_loc, (void*)&rec_loc, (void*)&fields,
                   (void*)&coef, (void*)&flags, (void*)&out };
  hipLaunchCooperativeKernel((void*)elastic_p2p, dim3(NBLOCKS), dim3(512),
                             args, 0, stream);
}